// Round 7
// baseline (185.171 us; speedup 1.0000x reference)
//
#include <hip/hip_runtime.h>
#include <math.h>

#define TPB 256
#define NBK_MAX 512   // max dst buckets (128 nodes each)
#define CAP 4096      // fixed e2/col region per bucket (mean 2046, sigma~45 -> 45-sigma)
#define FILL_CAP 4096 // LDS col-buffer per bucket (== CAP)
#define SC_CH 16      // register-held edges per thread in bscatter
#define DMAX 64       // per-node adjacency: slot0=self, 1..deg neighbors, rest sentinel
// NOTE: col2 is ushort -> requires N < 65536 (N = 50000 here).

typedef short bf16x8 __attribute__((ext_vector_type(8)));
typedef float f32x4 __attribute__((ext_vector_type(4)));

__device__ __forceinline__ unsigned short rne_bf16(float f) {
  unsigned u = __float_as_uint(f);
  return (unsigned short)((u + 0x7fffu + ((u >> 16) & 1u)) >> 16);
}
__device__ __forceinline__ float bf16_f(unsigned short v) {
  return __uint_as_float((unsigned)v << 16);
}
__device__ __forceinline__ float blo(unsigned u) { return __uint_as_float(u << 16); }
__device__ __forceinline__ float bhi(unsigned u) { return __uint_as_float(u & 0xffff0000u); }
// fast tanh: (e-1)*rcp(e+1), e=exp(2x), x clamped to +-15; abs err ~1e-7.
__device__ __forceinline__ float ftanh(float x) {
  float xc = fminf(fmaxf(x, -15.f), 15.f);
  float e = __expf(2.f * xc);
  return (e - 1.f) * __builtin_amdgcn_rcpf(e + 1.f);
}

// ---------------- init: bucket cursors + zero sentinel rows of h1,h2 ----------------
__global__ __launch_bounds__(TPB) void k_init(int* __restrict__ gcur,
                                              unsigned short* __restrict__ h1,
                                              unsigned short* __restrict__ h2,
                                              int NBK, int N) {
  int i = blockIdx.x * TPB + threadIdx.x;
  if (i < NBK) gcur[i] = i * CAP;
  if (blockIdx.x == 0 && threadIdx.x < 64) {
    unsigned short* hz = (threadIdx.x < 32) ? h1 : h2;
    ((unsigned*)(hz + ((size_t)N << 6)))[threadIdx.x & 31] = 0;  // zero sentinel row [N]
  }
}

// ---------------- scatter edges into fixed-capacity bucket regions of e2 ----------------
// Per-tile LDS histogram -> one atomic range-reservation per bucket -> ranked
// scatter. Contiguous line-granular writes (round-5 lesson: direct 2B scatter
// causes 28x write amplification + cross-XCD atomic ping-pong).
__global__ __launch_bounds__(TPB) void k_bscatter(const int* __restrict__ src,
                                                  const int* __restrict__ dst,
                                                  int* __restrict__ gcur,
                                                  unsigned* __restrict__ e2,
                                                  int E, int NBK) {
  __shared__ int h[NBK_MAX];
  __shared__ int base[NBK_MAX];
  int tid = threadIdx.x, blk = blockIdx.x, G = gridDim.x;
  int chunk = (E + G - 1) / G, lo = blk * chunk, hi = min(E, lo + chunk);
  for (int t0 = lo; t0 < hi; t0 += TPB * SC_CH) {
    int sv[SC_CH], dv[SC_CH];
    for (int b = tid; b < NBK; b += TPB) h[b] = 0;
    __syncthreads();
#pragma unroll
    for (int u = 0; u < SC_CH; ++u) {
      int e = t0 + u * TPB + tid;
      if (e < hi) {
        dv[u] = dst[e];
        sv[u] = src[e];
        atomicAdd(&h[dv[u] >> 7], 1);
      } else {
        dv[u] = -1;
      }
    }
    __syncthreads();
    for (int b = tid; b < NBK; b += TPB) {
      int c = h[b];
      if (c) {
        int o = atomicAdd(&gcur[b], c);
        base[b] = min(o, (b + 1) * CAP - c);  // never escapes the region
      }
    }
    __syncthreads();
    for (int b = tid; b < NBK; b += TPB) h[b] = 0;
    __syncthreads();
#pragma unroll
    for (int u = 0; u < SC_CH; ++u) {
      if (dv[u] >= 0) {
        int bk = dv[u] >> 7;
        int r = atomicAdd(&h[bk], 1);
        e2[base[bk] + r] = ((unsigned)sv[u] << 7) | (unsigned)(dv[u] & 127);
      }
    }
    __syncthreads();
  }
}

// ---------------- per-bucket count/scan/dinv + fixed-stride ushort col2 fill ----------------
// col2[node*64]: slot 0 = node itself (self-loop), slots 1..deg = neighbor srcs,
// rest = sentinel N (H'[N] is a zero row).
__global__ __launch_bounds__(TPB) void k_build(const unsigned* __restrict__ e2,
                                               const int* __restrict__ gcur,
                                               float* __restrict__ dinv,
                                               unsigned short* __restrict__ col2, int N) {
  __shared__ int c[128], sc[128], cur[128];
  __shared__ int buf[FILL_CAP];
  int tid = threadIdx.x, b = blockIdx.x;
  int st = b * CAP;
  int en = min(gcur[b], st + FILL_CAP);
  if (tid < 128) c[tid] = 0;
  __syncthreads();
  for (int i = st + tid; i < en; i += TPB) atomicAdd(&c[e2[i] & 127u], 1);
  __syncthreads();
  if (tid < 128) sc[tid] = c[tid];
  __syncthreads();
  for (int o = 1; o < 128; o <<= 1) {
    int v = (tid >= o && tid < 128) ? sc[tid - o] : 0;
    __syncthreads();
    if (tid < 128) sc[tid] += v;
    __syncthreads();
  }
  if (tid < 128) {
    cur[tid] = sc[tid] - c[tid];
    int node = b * 128 + tid;
    if (node < N) dinv[node] = rsqrtf((float)(c[tid] + 1));  // +1 self-loop
  }
  __syncthreads();
  for (int i = st + tid; i < en; i += TPB) {
    unsigned v = e2[i];
    int p = atomicAdd(&cur[v & 127u], 1);
    buf[p] = (int)(v >> 7);
  }
  __syncthreads();
  // packed uint stores: 2 ushort slots per store
  for (int i = tid; i < 128 * 32; i += TPB) {
    int nl = i >> 5, kk = i & 31;
    int node = b * 128 + nl;
    if (node < N) {
      int cc = c[nl], base0 = sc[nl] - cc;
      int k0 = kk * 2, k1 = kk * 2 + 1;
      unsigned v0 = (k0 == 0) ? (unsigned)node
                              : ((k0 - 1 < cc) ? (unsigned)buf[base0 + k0 - 1] : (unsigned)N);
      unsigned v1 = (k1 - 1 < cc) ? (unsigned)buf[base0 + k1 - 1] : (unsigned)N;
      ((unsigned*)col2)[((size_t)node << 5) + kk] = v0 | (v1 << 16);
    }
  }
}

// ---------------- MFMA GEMM with in-kernel W split; dinv-prescaled output ----------------
template <int K, bool AF32>
__global__ __launch_bounds__(TPB) void k_mm(const void* __restrict__ Ap,
                                            const float* __restrict__ W,
                                            const float* __restrict__ dinv,
                                            unsigned short* __restrict__ Hout, int N) {
  constexpr int P = K + 8;  // LDS pitch: conflict-free b128 frag reads
  __shared__ unsigned short sHi[64 * P];
  __shared__ unsigned short sLo[64 * P];
  int tid = threadIdx.x;
  for (int i = tid; i < K * 64; i += TPB) {
    int k = i >> 6, n = i & 63;  // coalesced read of W
    float w = W[i];
    unsigned short hb = rne_bf16(w);
    sHi[n * P + k] = hb;
    sLo[n * P + k] = rne_bf16(w - bf16_f(hb));
  }
  __syncthreads();
  int wave = tid >> 6, lane = tid & 63;
  int oct = lane >> 4, l15 = lane & 15;
  int base = blockIdx.x * 64 + wave * 16;
  int arow = base + l15;
  if (arow >= N) arow = N - 1;
  f32x4 acc[4] = {};
#pragma unroll
  for (int s = 0; s < K / 32; ++s) {
    bf16x8 ahi, alo;
    if (AF32) {
      const float* ap = (const float*)Ap + (size_t)arow * K + s * 32 + oct * 8;
      float4 f0 = *(const float4*)ap;
      float4 f1 = *(const float4*)(ap + 4);
      float fv[8] = {f0.x, f0.y, f0.z, f0.w, f1.x, f1.y, f1.z, f1.w};
#pragma unroll
      for (int j = 0; j < 8; ++j) {
        unsigned short hb = rne_bf16(fv[j]);
        ahi[j] = (short)hb;
        alo[j] = (short)rne_bf16(fv[j] - bf16_f(hb));
      }
    } else {
      ahi = *(const bf16x8*)((const unsigned short*)Ap + (size_t)arow * K + s * 32 + oct * 8);
    }
#pragma unroll
    for (int t = 0; t < 4; ++t) {
      bf16x8 bh = *(const bf16x8*)(sHi + (t * 16 + l15) * P + s * 32 + oct * 8);
      bf16x8 bl = *(const bf16x8*)(sLo + (t * 16 + l15) * P + s * 32 + oct * 8);
      acc[t] = __builtin_amdgcn_mfma_f32_16x16x32_bf16(ahi, bh, acc[t], 0, 0, 0);
      acc[t] = __builtin_amdgcn_mfma_f32_16x16x32_bf16(ahi, bl, acc[t], 0, 0, 0);
      if (AF32)
        acc[t] = __builtin_amdgcn_mfma_f32_16x16x32_bf16(alo, bh, acc[t], 0, 0, 0);
    }
  }
#pragma unroll
  for (int r = 0; r < 4; ++r) {
    int row = base + oct * 4 + r;
    if (row < N) {
      float dv = dinv[row];  // same addr across l15 lanes -> broadcast
#pragma unroll
      for (int t = 0; t < 4; ++t)
        Hout[(size_t)row * 64 + t * 16 + l15] = rne_bf16(acc[t][r] * dv);
    }
  }
}

// ---------------- branchless gather macros (round-4 shape) ----------------
// Lane = (half = lane>>5 edge parity, f2 = lane&31 feature pair). Addresses from
// v_readlane + 32-bit saddr offsets. 32 slots processed unconditionally: sentinel
// slots gather the zero row H'[N] (exact +0.0). Wave-uniform tail for cnt>32.

#define AQ_ISSUE(J, HVS)                                                        \
  {                                                                             \
    _Pragma("unroll") for (int g = 0; g < 8; ++g) {                             \
      int s0 = __builtin_amdgcn_readlane(sv[J], g);                             \
      int s1 = __builtin_amdgcn_readlane(sv[J], 8 + g);                         \
      unsigned off0 = ((unsigned)(half ? s1 : s0) << 7) + foff;                 \
      HVS[0][g] = *(const unsigned*)(Hb + off0);                                \
    }                                                                           \
    _Pragma("unroll") for (int g = 0; g < 8; ++g) {                             \
      int s0 = __builtin_amdgcn_readlane(sv[J], 16 + g);                        \
      int s1 = __builtin_amdgcn_readlane(sv[J], 24 + g);                        \
      unsigned off1 = ((unsigned)(half ? s1 : s0) << 7) + foff;                 \
      HVS[1][g] = *(const unsigned*)(Hb + off1);                                \
    }                                                                           \
  }

#define AQ_SUM(J, HVS)                                                          \
  float x = 0.f, y = 0.f;                                                       \
  _Pragma("unroll") for (int g = 0; g < 8; ++g) {                               \
    x += blo(HVS[0][g]);                                                        \
    y += bhi(HVS[0][g]);                                                        \
  }                                                                             \
  _Pragma("unroll") for (int g = 0; g < 8; ++g) {                               \
    x += blo(HVS[1][g]);                                                        \
    y += bhi(HVS[1][g]);                                                        \
  }                                                                             \
  if (cnt[J] > 32) { /* ~2 nodes in 50k, wave-uniform branch */                 \
    for (int t = 32; t < cnt[J]; t += 16) {                                     \
      unsigned tv[8];                                                           \
      _Pragma("unroll") for (int g = 0; g < 8; ++g) {                           \
        int s0 = __builtin_amdgcn_readlane(sv[J], t + g);                       \
        int s1 = __builtin_amdgcn_readlane(sv[J], t + 8 + g);                   \
        unsigned offt = ((unsigned)(half ? s1 : s0) << 7) + foff;               \
        tv[g] = *(const unsigned*)(Hb + offt);                                  \
      }                                                                         \
      _Pragma("unroll") for (int g = 0; g < 8; ++g) {                           \
        x += blo(tv[g]);                                                        \
        y += bhi(tv[g]);                                                        \
      }                                                                         \
    }                                                                           \
  }                                                                             \
  x += __shfl_xor(x, 32);                                                       \
  y += __shfl_xor(y, 32);                                                       \
  float di_ = rsqrtf((float)cnt[J]);                                            \
  float yx_ = ftanh(di_ * x + bf.x);                                            \
  float yy_ = ftanh(di_ * y + bf.y);

// ---------------- fused agg1 + mm2 (8 nodes/wave, padded MFMA tile) ----------------
// 8 nodes/wave restores the 6250-wave grid (76% occupancy ceiling vs 38% at
// 16/wave). The MFMA A-tile is 16 rows: rows 0..7 = this wave's nodes, rows
// 8..15 = stale LDS (their MFMA output is never stored -- row-independent math,
// ~80cy of wasted MFMA per wave, noise). Same op order as k_mm<64> ->
// bitwise-identical h2. No barriers after W2 staging.

#define AM_ACC(J, HVS)                                                          \
  {                                                                             \
    AQ_SUM(J, HVS)                                                              \
    if (half == 0) {                                                            \
      unsigned pk_ = (unsigned)rne_bf16(yx_) | ((unsigned)rne_bf16(yy_) << 16); \
      ((unsigned*)(sA2 + ((wid << 4) + (J)) * 72))[f2] = pk_;                   \
    }                                                                           \
    if (lane == 0) sDi[(wid << 4) + (J)] = di_;                                 \
  }

__global__ __launch_bounds__(TPB, 6) void k_aggmm(const unsigned short* __restrict__ H,
                                                  const unsigned short* __restrict__ col2,
                                                  const float* __restrict__ bias,
                                                  const float* __restrict__ W2,
                                                  unsigned short* __restrict__ Hout,
                                                  int N) {
  __shared__ unsigned short sHi2[64 * 72];
  __shared__ unsigned short sLo2[64 * 72];
  __shared__ unsigned short sA2[4 * 16 * 72];  // per-wave 16-row tile (rows 8-15 pad)
  __shared__ float sDi[4 * 16];
  int tid = threadIdx.x;
  int wid = tid >> 6, lane = tid & 63;
  int f2 = lane & 31, half = lane >> 5;
  // stage W2 hi/lo split (identical to k_mm<64> staging)
  for (int i = tid; i < 64 * 64; i += TPB) {
    int k = i >> 6, n = i & 63;
    float w = W2[i];
    unsigned short hb = rne_bf16(w);
    sHi2[n * 72 + k] = hb;
    sLo2[n * 72 + k] = rne_bf16(w - bf16_f(hb));
  }
  __syncthreads();  // only barrier
  float2 bf = *(const float2*)(bias + f2 * 2);  // feats 2*f2, 2*f2+1
  const char* Hb = (const char*)H;
  unsigned foff = (unsigned)(f2 * 4);

  int wqb = (blockIdx.x * 4 + wid) * 8;
  if (wqb >= N) return;

  int idx[8];
#pragma unroll
  for (int j = 0; j < 8; ++j) idx[j] = min(wqb + j, N - 1);
  int sv[8];
#pragma unroll
  for (int j = 0; j < 8; ++j) sv[j] = (int)col2[((size_t)idx[j] << 6) + lane];
  int cnt[8];
#pragma unroll
  for (int j = 0; j < 8; ++j) {
    unsigned long long mb_ = __ballot(sv[j] != N);
    cnt[j] = __builtin_amdgcn_readfirstlane((int)__popcll(mb_));
  }
  unsigned hvA[2][8], hvB[2][8];
  AQ_ISSUE(0, hvA)
  AQ_ISSUE(1, hvB)
  AM_ACC(0, hvA)
  AQ_ISSUE(2, hvA)
  AM_ACC(1, hvB)
  AQ_ISSUE(3, hvB)
  AM_ACC(2, hvA)
  AQ_ISSUE(4, hvA)
  AM_ACC(3, hvB)
  AQ_ISSUE(5, hvB)
  AM_ACC(4, hvA)
  AQ_ISSUE(6, hvA)
  AM_ACC(5, hvB)
  AQ_ISSUE(7, hvB)
  AM_ACC(6, hvA)
  AM_ACC(7, hvB)

  // ---- fused mm2: A = this wave's 16-row tile (8 valid), B = sHi2/sLo2 ----
  int oct = lane >> 4, l15 = lane & 15;
  f32x4 macc[4] = {};
  const unsigned short* aRow = sA2 + ((wid << 4) + l15) * 72;
#pragma unroll
  for (int s = 0; s < 2; ++s) {
    bf16x8 ahi = *(const bf16x8*)(aRow + s * 32 + oct * 8);
#pragma unroll
    for (int t = 0; t < 4; ++t) {
      bf16x8 bh = *(const bf16x8*)(sHi2 + (t * 16 + l15) * 72 + s * 32 + oct * 8);
      bf16x8 bl = *(const bf16x8*)(sLo2 + (t * 16 + l15) * 72 + s * 32 + oct * 8);
      macc[t] = __builtin_amdgcn_mfma_f32_16x16x32_bf16(ahi, bh, macc[t], 0, 0, 0);
      macc[t] = __builtin_amdgcn_mfma_f32_16x16x32_bf16(ahi, bl, macc[t], 0, 0, 0);
    }
  }
#pragma unroll
  for (int r = 0; r < 4; ++r) {
    int row = oct * 4 + r;  // tile-local 0..15; only 0..7 are real nodes
    int node = wqb + row;
    if (row < 8 && node < N) {
      float dvv = sDi[(wid << 4) + row];
#pragma unroll
      for (int t = 0; t < 4; ++t)
        Hout[((size_t)node << 6) + t * 16 + l15] = rne_bf16(macc[t][r] * dvv);
    }
  }
}

// ---------------- agg2 + fused MLP head (wave-local, 3-deep pipeline) ----------------
#define AG_ACC(J, HVS)                                                          \
  {                                                                             \
    AQ_SUM(J, HVS)                                                              \
    if (half == 0) {                                                            \
      float* sp_ = sA + ((wid << 3) + (J)) * 64 + f2 * 2;                       \
      sp_[0] = yx_;                                                             \
      sp_[1] = yy_;                                                             \
    }                                                                           \
  }

__global__ __launch_bounds__(TPB, 6) void k_aggfc(const unsigned short* __restrict__ H,
                                                  const unsigned short* __restrict__ col2,
                                                  const float* __restrict__ bias,
                                                  const float* __restrict__ fw1,
                                                  const float* __restrict__ fb1,
                                                  const float* __restrict__ fw2,
                                                  const float* __restrict__ fb2,
                                                  float* __restrict__ fout, int N) {
  __shared__ float sw1t[32 * 66];  // [m][k] pitch 66 (2-way aliasing = free)
  __shared__ float sb1[32];
  __shared__ float sw2[32];
  __shared__ float sA[4 * 8 * 64];  // per-wave activation rows
  int tid = threadIdx.x;
  int wid = tid >> 6, lane = tid & 63;
  int f2 = lane & 31, half = lane >> 5;
  for (int i = tid; i < 32 * 64; i += TPB) {
    int j = i >> 6, k = i & 63;
    sw1t[j * 66 + k] = fw1[k * 32 + j];
  }
  if (tid < 32) { sb1[tid] = fb1[tid]; sw2[tid] = fw2[tid]; }
  float b2v = fb2[0];
  __syncthreads();  // only barrier: weight staging
  float2 bf = *(const float2*)(bias + f2 * 2);  // feats 2*f2, 2*f2+1
  const char* Hb = (const char*)H;
  unsigned foff = (unsigned)(f2 * 4);

  int qb = (blockIdx.x * 4 + wid) * 8;
  if (qb >= N) return;  // safe: no barriers after this point

  int idx[8];
#pragma unroll
  for (int j = 0; j < 8; ++j) idx[j] = min(qb + j, N - 1);
  int sv[8];
#pragma unroll
  for (int j = 0; j < 8; ++j) sv[j] = (int)col2[((size_t)idx[j] << 6) + lane];
  int cnt[8];
#pragma unroll
  for (int j = 0; j < 8; ++j) {
    unsigned long long mb_ = __ballot(sv[j] != N);
    cnt[j] = __builtin_amdgcn_readfirstlane((int)__popcll(mb_));
  }
  // 3-deep pipeline: at each ACC(j), loads for j+1,j+2 (and j+3 issued right
  // after) are in flight -> 48 outstanding loads/wave. VGPR ~60 (< 64 cliff).
  unsigned hvA[2][8], hvB[2][8], hvC[2][8];
  AQ_ISSUE(0, hvA)
  AQ_ISSUE(1, hvB)
  AQ_ISSUE(2, hvC)
  AG_ACC(0, hvA)
  AQ_ISSUE(3, hvA)
  AG_ACC(1, hvB)
  AQ_ISSUE(4, hvB)
  AG_ACC(2, hvC)
  AQ_ISSUE(5, hvC)
  AG_ACC(3, hvA)
  AQ_ISSUE(6, hvA)
  AG_ACC(4, hvB)
  AQ_ISSUE(7, hvB)
  AG_ACC(5, hvC)
  AG_ACC(6, hvA)
  AG_ACC(7, hvB)

  int m = lane & 31;
#pragma unroll
  for (int p = 0; p < 4; ++p) {
    int nl = p * 2 + half;  // node-local 0..7, halves take alternate nodes
    int node = qb + nl;
    float acc = sb1[m];
    const float2* ar = (const float2*)(sA + ((wid << 3) + nl) * 64);  // broadcast
    const float2* wr = (const float2*)(sw1t + m * 66);                // 2-way (free)
#pragma unroll
    for (int k2 = 0; k2 < 32; ++k2) {
      float2 av = ar[k2];
      float2 wv = wr[k2];
      acc += av.x * wv.x + av.y * wv.y;
    }
    float t = ftanh(acc) * sw2[m];
#pragma unroll
    for (int o = 1; o < 32; o <<= 1) t += __shfl_xor(t, o);  // o=1..16: stays in half
    if (m == 0 && node < N) fout[node] = t + b2v;
  }
}

// ================= host =================

extern "C" void kernel_launch(void* const* d_in, const int* in_sizes, int n_in,
                              void* d_out, int out_size, void* d_ws, size_t ws_size,
                              hipStream_t stream) {
  const float* x   = (const float*)d_in[0];
  const int*   ei  = (const int*)d_in[1];
  const float* w1  = (const float*)d_in[2];
  const float* b1  = (const float*)d_in[3];
  const float* w2  = (const float*)d_in[4];
  const float* b2  = (const float*)d_in[5];
  const float* fw1 = (const float*)d_in[6];
  const float* fb1 = (const float*)d_in[7];
  const float* fw2 = (const float*)d_in[8];
  const float* fb2 = (const float*)d_in[9];
  float* out = (float*)d_out;

  int N = in_sizes[0] / 128;
  int E = in_sizes[1] / 2;
  const int* src = ei;
  const int* dst = ei + E;

  const int G   = 256;                // blocks for the edge scatter (write locality)
  const int NBK = (N + 127) / 128;    // 391 buckets

  char* p = (char*)d_ws;
  size_t off = 0;
  auto take = [&](size_t bytes) -> void* {
    void* r = p + off;
    off += (bytes + 255) & ~(size_t)255;
    return r;
  };
  int*            gcur = (int*)take((size_t)NBK * 4);
  float*          dinv = (float*)take((size_t)N * 4);
  unsigned*       e2   = (unsigned*)take((size_t)NBK * CAP * 4);
  unsigned short* col2 = (unsigned short*)take((size_t)N * DMAX * 2);
  unsigned short* h1   = (unsigned short*)take((size_t)(N + 1) * 64 * 2);  // +sentinel row N
  unsigned short* h2   = (unsigned short*)take((size_t)(N + 1) * 64 * 2);  // +sentinel row N
  (void)ws_size; (void)n_in; (void)out_size;

  // graph build: 3 kernels (fixed-capacity buckets -> line-granular writes)
  k_init<<<(NBK + TPB - 1) / TPB, TPB, 0, stream>>>(gcur, h1, h2, NBK, N);
  k_bscatter<<<G, TPB, 0, stream>>>(src, dst, gcur, e2, E, NBK);
  k_build<<<NBK, TPB, 0, stream>>>(e2, gcur, dinv, col2, N);

  // network: mm1 -> (agg1+mm2 fused) -> (agg2+FC fused)
  int gmm  = (N + 63) / 64;
  int gagg = (N + 31) / 32;  // 8 nodes/wave * 4 waves
  k_mm<128, true><<<gmm, TPB, 0, stream>>>(x, w1, dinv, h1, N);
  k_aggmm<<<gagg, TPB, 0, stream>>>(h1, col2, b1, w2, h2, N);
  k_aggfc<<<gagg, TPB, 0, stream>>>(h2, col2, b2, fw1, fb1, fw2, fb2, out, N);
}

// Round 8
// 174.167 us; speedup vs baseline: 1.0632x; 1.0632x over previous
//
#include <hip/hip_runtime.h>
#include <math.h>

#define TPB 256
#define NBK_MAX 512   // max dst buckets (128 nodes each)
#define CAP 4096      // fixed e2/col region per bucket (mean 2046, sigma~45 -> 45-sigma)
#define FILL_CAP 4096 // LDS col-buffer per bucket (== CAP)
#define SC_CH 16      // register-held edges per thread in bscatter
#define DMAX 64       // per-node adjacency: slot0=self, 1..deg neighbors, rest sentinel
// NOTE: col2 is ushort -> requires N < 65536 (N = 50000 here).

typedef short bf16x8 __attribute__((ext_vector_type(8)));
typedef float f32x4 __attribute__((ext_vector_type(4)));

__device__ __forceinline__ unsigned short rne_bf16(float f) {
  unsigned u = __float_as_uint(f);
  return (unsigned short)((u + 0x7fffu + ((u >> 16) & 1u)) >> 16);
}
__device__ __forceinline__ float bf16_f(unsigned short v) {
  return __uint_as_float((unsigned)v << 16);
}
__device__ __forceinline__ float blo(unsigned u) { return __uint_as_float(u << 16); }
__device__ __forceinline__ float bhi(unsigned u) { return __uint_as_float(u & 0xffff0000u); }
// fast tanh: (e-1)*rcp(e+1), e=exp(2x), x clamped to +-15; abs err ~1e-7.
__device__ __forceinline__ float ftanh(float x) {
  float xc = fminf(fmaxf(x, -15.f), 15.f);
  float e = __expf(2.f * xc);
  return (e - 1.f) * __builtin_amdgcn_rcpf(e + 1.f);
}

// ---------------- init: bucket cursors + zero sentinel rows of h1,h2 ----------------
__global__ __launch_bounds__(TPB) void k_init(int* __restrict__ gcur,
                                              unsigned short* __restrict__ h1,
                                              unsigned short* __restrict__ h2,
                                              int NBK, int N) {
  int i = blockIdx.x * TPB + threadIdx.x;
  if (i < NBK) gcur[i] = i * CAP;
  if (blockIdx.x == 0 && threadIdx.x < 64) {
    unsigned short* hz = (threadIdx.x < 32) ? h1 : h2;
    ((unsigned*)(hz + ((size_t)N << 6)))[threadIdx.x & 31] = 0;  // zero sentinel row [N]
  }
}

// ---------------- scatter edges into fixed-capacity bucket regions of e2 ----------------
// Per-tile LDS histogram -> one atomic range-reservation per bucket -> ranked
// scatter. Contiguous line-granular writes (round-5 lesson: direct 2B scatter
// causes 28x write amplification + cross-XCD atomic ping-pong).
__global__ __launch_bounds__(TPB) void k_bscatter(const int* __restrict__ src,
                                                  const int* __restrict__ dst,
                                                  int* __restrict__ gcur,
                                                  unsigned* __restrict__ e2,
                                                  int E, int NBK) {
  __shared__ int h[NBK_MAX];
  __shared__ int base[NBK_MAX];
  int tid = threadIdx.x, blk = blockIdx.x, G = gridDim.x;
  int chunk = (E + G - 1) / G, lo = blk * chunk, hi = min(E, lo + chunk);
  for (int t0 = lo; t0 < hi; t0 += TPB * SC_CH) {
    int sv[SC_CH], dv[SC_CH];
    for (int b = tid; b < NBK; b += TPB) h[b] = 0;
    __syncthreads();
#pragma unroll
    for (int u = 0; u < SC_CH; ++u) {
      int e = t0 + u * TPB + tid;
      if (e < hi) {
        dv[u] = dst[e];
        sv[u] = src[e];
        atomicAdd(&h[dv[u] >> 7], 1);
      } else {
        dv[u] = -1;
      }
    }
    __syncthreads();
    for (int b = tid; b < NBK; b += TPB) {
      int c = h[b];
      if (c) {
        int o = atomicAdd(&gcur[b], c);
        base[b] = min(o, (b + 1) * CAP - c);  // never escapes the region
      }
    }
    __syncthreads();
    for (int b = tid; b < NBK; b += TPB) h[b] = 0;
    __syncthreads();
#pragma unroll
    for (int u = 0; u < SC_CH; ++u) {
      if (dv[u] >= 0) {
        int bk = dv[u] >> 7;
        int r = atomicAdd(&h[bk], 1);
        e2[base[bk] + r] = ((unsigned)sv[u] << 7) | (unsigned)(dv[u] & 127);
      }
    }
    __syncthreads();
  }
}

// ---------------- per-bucket count/scan/dinv + fixed-stride ushort col2 fill ----------------
// col2[node*64]: slot 0 = node itself (self-loop), slots 1..deg = neighbor srcs,
// rest = sentinel N (H'[N] is a zero row).
__global__ __launch_bounds__(TPB) void k_build(const unsigned* __restrict__ e2,
                                               const int* __restrict__ gcur,
                                               float* __restrict__ dinv,
                                               unsigned short* __restrict__ col2, int N) {
  __shared__ int c[128], sc[128], cur[128];
  __shared__ int buf[FILL_CAP];
  int tid = threadIdx.x, b = blockIdx.x;
  int st = b * CAP;
  int en = min(gcur[b], st + FILL_CAP);
  if (tid < 128) c[tid] = 0;
  __syncthreads();
  for (int i = st + tid; i < en; i += TPB) atomicAdd(&c[e2[i] & 127u], 1);
  __syncthreads();
  if (tid < 128) sc[tid] = c[tid];
  __syncthreads();
  for (int o = 1; o < 128; o <<= 1) {
    int v = (tid >= o && tid < 128) ? sc[tid - o] : 0;
    __syncthreads();
    if (tid < 128) sc[tid] += v;
    __syncthreads();
  }
  if (tid < 128) {
    cur[tid] = sc[tid] - c[tid];
    int node = b * 128 + tid;
    if (node < N) dinv[node] = rsqrtf((float)(c[tid] + 1));  // +1 self-loop
  }
  __syncthreads();
  for (int i = st + tid; i < en; i += TPB) {
    unsigned v = e2[i];
    int p = atomicAdd(&cur[v & 127u], 1);
    buf[p] = (int)(v >> 7);
  }
  __syncthreads();
  // packed uint stores: 2 ushort slots per store
  for (int i = tid; i < 128 * 32; i += TPB) {
    int nl = i >> 5, kk = i & 31;
    int node = b * 128 + nl;
    if (node < N) {
      int cc = c[nl], base0 = sc[nl] - cc;
      int k0 = kk * 2, k1 = kk * 2 + 1;
      unsigned v0 = (k0 == 0) ? (unsigned)node
                              : ((k0 - 1 < cc) ? (unsigned)buf[base0 + k0 - 1] : (unsigned)N);
      unsigned v1 = (k1 - 1 < cc) ? (unsigned)buf[base0 + k1 - 1] : (unsigned)N;
      ((unsigned*)col2)[((size_t)node << 5) + kk] = v0 | (v1 << 16);
    }
  }
}

// ---------------- MFMA GEMM with in-kernel W split; dinv-prescaled output ----------------
template <int K, bool AF32>
__global__ __launch_bounds__(TPB) void k_mm(const void* __restrict__ Ap,
                                            const float* __restrict__ W,
                                            const float* __restrict__ dinv,
                                            unsigned short* __restrict__ Hout, int N) {
  constexpr int P = K + 8;  // LDS pitch: conflict-free b128 frag reads
  __shared__ unsigned short sHi[64 * P];
  __shared__ unsigned short sLo[64 * P];
  int tid = threadIdx.x;
  for (int i = tid; i < K * 64; i += TPB) {
    int k = i >> 6, n = i & 63;  // coalesced read of W
    float w = W[i];
    unsigned short hb = rne_bf16(w);
    sHi[n * P + k] = hb;
    sLo[n * P + k] = rne_bf16(w - bf16_f(hb));
  }
  __syncthreads();
  int wave = tid >> 6, lane = tid & 63;
  int oct = lane >> 4, l15 = lane & 15;
  int base = blockIdx.x * 64 + wave * 16;
  int arow = base + l15;
  if (arow >= N) arow = N - 1;
  f32x4 acc[4] = {};
#pragma unroll
  for (int s = 0; s < K / 32; ++s) {
    bf16x8 ahi, alo;
    if (AF32) {
      const float* ap = (const float*)Ap + (size_t)arow * K + s * 32 + oct * 8;
      float4 f0 = *(const float4*)ap;
      float4 f1 = *(const float4*)(ap + 4);
      float fv[8] = {f0.x, f0.y, f0.z, f0.w, f1.x, f1.y, f1.z, f1.w};
#pragma unroll
      for (int j = 0; j < 8; ++j) {
        unsigned short hb = rne_bf16(fv[j]);
        ahi[j] = (short)hb;
        alo[j] = (short)rne_bf16(fv[j] - bf16_f(hb));
      }
    } else {
      ahi = *(const bf16x8*)((const unsigned short*)Ap + (size_t)arow * K + s * 32 + oct * 8);
    }
#pragma unroll
    for (int t = 0; t < 4; ++t) {
      bf16x8 bh = *(const bf16x8*)(sHi + (t * 16 + l15) * P + s * 32 + oct * 8);
      bf16x8 bl = *(const bf16x8*)(sLo + (t * 16 + l15) * P + s * 32 + oct * 8);
      acc[t] = __builtin_amdgcn_mfma_f32_16x16x32_bf16(ahi, bh, acc[t], 0, 0, 0);
      acc[t] = __builtin_amdgcn_mfma_f32_16x16x32_bf16(ahi, bl, acc[t], 0, 0, 0);
      if (AF32)
        acc[t] = __builtin_amdgcn_mfma_f32_16x16x32_bf16(alo, bh, acc[t], 0, 0, 0);
    }
  }
#pragma unroll
  for (int r = 0; r < 4; ++r) {
    int row = base + oct * 4 + r;
    if (row < N) {
      float dv = dinv[row];  // same addr across l15 lanes -> broadcast
#pragma unroll
      for (int t = 0; t < 4; ++t)
        Hout[(size_t)row * 64 + t * 16 + l15] = rne_bf16(acc[t][r] * dv);
    }
  }
}

// ---------------- branchless gather macros (round-4 shape) ----------------
// Lane = (half = lane>>5 edge parity, f2 = lane&31 feature pair). Addresses from
// v_readlane + 32-bit saddr offsets. 32 slots processed unconditionally: sentinel
// slots gather the zero row H'[N] (exact +0.0). Wave-uniform tail for cnt>32.

#define AQ_ISSUE(J, HVS)                                                        \
  {                                                                             \
    _Pragma("unroll") for (int g = 0; g < 8; ++g) {                             \
      int s0 = __builtin_amdgcn_readlane(sv[J], g);                             \
      int s1 = __builtin_amdgcn_readlane(sv[J], 8 + g);                         \
      unsigned off0 = ((unsigned)(half ? s1 : s0) << 7) + foff;                 \
      HVS[0][g] = *(const unsigned*)(Hb + off0);                                \
    }                                                                           \
    _Pragma("unroll") for (int g = 0; g < 8; ++g) {                             \
      int s0 = __builtin_amdgcn_readlane(sv[J], 16 + g);                        \
      int s1 = __builtin_amdgcn_readlane(sv[J], 24 + g);                        \
      unsigned off1 = ((unsigned)(half ? s1 : s0) << 7) + foff;                 \
      HVS[1][g] = *(const unsigned*)(Hb + off1);                                \
    }                                                                           \
  }

#define AQ_SUM(J, HVS)                                                          \
  float x = 0.f, y = 0.f;                                                       \
  _Pragma("unroll") for (int g = 0; g < 8; ++g) {                               \
    x += blo(HVS[0][g]);                                                        \
    y += bhi(HVS[0][g]);                                                        \
  }                                                                             \
  _Pragma("unroll") for (int g = 0; g < 8; ++g) {                               \
    x += blo(HVS[1][g]);                                                        \
    y += bhi(HVS[1][g]);                                                        \
  }                                                                             \
  if (cnt[J] > 32) { /* ~2 nodes in 50k, wave-uniform branch */                 \
    for (int t = 32; t < cnt[J]; t += 16) {                                     \
      unsigned tv[8];                                                           \
      _Pragma("unroll") for (int g = 0; g < 8; ++g) {                           \
        int s0 = __builtin_amdgcn_readlane(sv[J], t + g);                       \
        int s1 = __builtin_amdgcn_readlane(sv[J], t + 8 + g);                   \
        unsigned offt = ((unsigned)(half ? s1 : s0) << 7) + foff;               \
        tv[g] = *(const unsigned*)(Hb + offt);                                  \
      }                                                                         \
      _Pragma("unroll") for (int g = 0; g < 8; ++g) {                           \
        x += blo(tv[g]);                                                        \
        y += bhi(tv[g]);                                                        \
      }                                                                         \
    }                                                                           \
  }                                                                             \
  x += __shfl_xor(x, 32);                                                       \
  y += __shfl_xor(y, 32);                                                       \
  float di_ = rsqrtf((float)cnt[J]);                                            \
  float yx_ = ftanh(di_ * x + bf.x);                                            \
  float yy_ = ftanh(di_ * y + bf.y);

// ---------------- fused agg1 + mm2 (8 nodes/wave, padded MFMA tile) ----------------
// 8 nodes/wave keeps the 6250-wave grid (76% occupancy ceiling vs 38% at
// 16/wave). The MFMA A-tile is 16 rows: rows 0..7 = this wave's nodes, rows
// 8..15 = stale LDS (their MFMA output is never stored -- row-independent math,
// ~80cy of wasted MFMA per wave, noise). Same op order as k_mm<64> ->
// bitwise-identical h2. No barriers after W2 staging.
// NOTE: no min-wave __launch_bounds__ -- round-7 lesson: occupancy bounds +
// deep pipelines force scratch spills (VGPR 40, +35MB scratch traffic).

#define AM_ACC(J, HVS)                                                          \
  {                                                                             \
    AQ_SUM(J, HVS)                                                              \
    if (half == 0) {                                                            \
      unsigned pk_ = (unsigned)rne_bf16(yx_) | ((unsigned)rne_bf16(yy_) << 16); \
      ((unsigned*)(sA2 + ((wid << 4) + (J)) * 72))[f2] = pk_;                   \
    }                                                                           \
    if (lane == 0) sDi[(wid << 4) + (J)] = di_;                                 \
  }

__global__ __launch_bounds__(TPB) void k_aggmm(const unsigned short* __restrict__ H,
                                               const unsigned short* __restrict__ col2,
                                               const float* __restrict__ bias,
                                               const float* __restrict__ W2,
                                               unsigned short* __restrict__ Hout,
                                               int N) {
  __shared__ unsigned short sHi2[64 * 72];
  __shared__ unsigned short sLo2[64 * 72];
  __shared__ unsigned short sA2[4 * 16 * 72];  // per-wave 16-row tile (rows 8-15 pad)
  __shared__ float sDi[4 * 16];
  int tid = threadIdx.x;
  int wid = tid >> 6, lane = tid & 63;
  int f2 = lane & 31, half = lane >> 5;
  // stage W2 hi/lo split (identical to k_mm<64> staging)
  for (int i = tid; i < 64 * 64; i += TPB) {
    int k = i >> 6, n = i & 63;
    float w = W2[i];
    unsigned short hb = rne_bf16(w);
    sHi2[n * 72 + k] = hb;
    sLo2[n * 72 + k] = rne_bf16(w - bf16_f(hb));
  }
  __syncthreads();  // only barrier
  float2 bf = *(const float2*)(bias + f2 * 2);  // feats 2*f2, 2*f2+1
  const char* Hb = (const char*)H;
  unsigned foff = (unsigned)(f2 * 4);

  int wqb = (blockIdx.x * 4 + wid) * 8;
  if (wqb >= N) return;

  int idx[8];
#pragma unroll
  for (int j = 0; j < 8; ++j) idx[j] = min(wqb + j, N - 1);
  int sv[8];
#pragma unroll
  for (int j = 0; j < 8; ++j) sv[j] = (int)col2[((size_t)idx[j] << 6) + lane];
  int cnt[8];
#pragma unroll
  for (int j = 0; j < 8; ++j) {
    unsigned long long mb_ = __ballot(sv[j] != N);
    cnt[j] = __builtin_amdgcn_readfirstlane((int)__popcll(mb_));
  }
  unsigned hvA[2][8], hvB[2][8];
  AQ_ISSUE(0, hvA)
  AQ_ISSUE(1, hvB)
  AM_ACC(0, hvA)
  AQ_ISSUE(2, hvA)
  AM_ACC(1, hvB)
  AQ_ISSUE(3, hvB)
  AM_ACC(2, hvA)
  AQ_ISSUE(4, hvA)
  AM_ACC(3, hvB)
  AQ_ISSUE(5, hvB)
  AM_ACC(4, hvA)
  AQ_ISSUE(6, hvA)
  AM_ACC(5, hvB)
  AQ_ISSUE(7, hvB)
  AM_ACC(6, hvA)
  AM_ACC(7, hvB)

  // ---- fused mm2: A = this wave's 16-row tile (8 valid), B = sHi2/sLo2 ----
  int oct = lane >> 4, l15 = lane & 15;
  f32x4 macc[4] = {};
  const unsigned short* aRow = sA2 + ((wid << 4) + l15) * 72;
#pragma unroll
  for (int s = 0; s < 2; ++s) {
    bf16x8 ahi = *(const bf16x8*)(aRow + s * 32 + oct * 8);
#pragma unroll
    for (int t = 0; t < 4; ++t) {
      bf16x8 bh = *(const bf16x8*)(sHi2 + (t * 16 + l15) * 72 + s * 32 + oct * 8);
      bf16x8 bl = *(const bf16x8*)(sLo2 + (t * 16 + l15) * 72 + s * 32 + oct * 8);
      macc[t] = __builtin_amdgcn_mfma_f32_16x16x32_bf16(ahi, bh, macc[t], 0, 0, 0);
      macc[t] = __builtin_amdgcn_mfma_f32_16x16x32_bf16(ahi, bl, macc[t], 0, 0, 0);
    }
  }
#pragma unroll
  for (int r = 0; r < 4; ++r) {
    int row = oct * 4 + r;  // tile-local 0..15; only 0..7 are real nodes
    int node = wqb + row;
    if (row < 8 && node < N) {
      float dvv = sDi[(wid << 4) + row];
#pragma unroll
      for (int t = 0; t < 4; ++t)
        Hout[((size_t)node << 6) + t * 16 + l15] = rne_bf16(macc[t][r] * dvv);
    }
  }
}

// ---------------- agg2 + fused MLP head (wave-local, 2-deep pipeline) ----------------
// Round-6 proven shape: 2-deep pipeline fits default register allocation, no
// spill. (3-deep + occupancy bound spilled in round 7 -- do not re-add.)
#define AG_ACC(J, HVS)                                                          \
  {                                                                             \
    AQ_SUM(J, HVS)                                                              \
    if (half == 0) {                                                            \
      float* sp_ = sA + ((wid << 3) + (J)) * 64 + f2 * 2;                       \
      sp_[0] = yx_;                                                             \
      sp_[1] = yy_;                                                             \
    }                                                                           \
  }

__global__ __launch_bounds__(TPB) void k_aggfc(const unsigned short* __restrict__ H,
                                               const unsigned short* __restrict__ col2,
                                               const float* __restrict__ bias,
                                               const float* __restrict__ fw1,
                                               const float* __restrict__ fb1,
                                               const float* __restrict__ fw2,
                                               const float* __restrict__ fb2,
                                               float* __restrict__ fout, int N) {
  __shared__ float sw1t[32 * 66];  // [m][k] pitch 66 (2-way aliasing = free)
  __shared__ float sb1[32];
  __shared__ float sw2[32];
  __shared__ float sA[4 * 8 * 64];  // per-wave activation rows
  int tid = threadIdx.x;
  int wid = tid >> 6, lane = tid & 63;
  int f2 = lane & 31, half = lane >> 5;
  for (int i = tid; i < 32 * 64; i += TPB) {
    int j = i >> 6, k = i & 63;
    sw1t[j * 66 + k] = fw1[k * 32 + j];
  }
  if (tid < 32) { sb1[tid] = fb1[tid]; sw2[tid] = fw2[tid]; }
  float b2v = fb2[0];
  __syncthreads();  // only barrier: weight staging
  float2 bf = *(const float2*)(bias + f2 * 2);  // feats 2*f2, 2*f2+1
  const char* Hb = (const char*)H;
  unsigned foff = (unsigned)(f2 * 4);

  int qb = (blockIdx.x * 4 + wid) * 8;
  if (qb >= N) return;  // safe: no barriers after this point

  int idx[8];
#pragma unroll
  for (int j = 0; j < 8; ++j) idx[j] = min(qb + j, N - 1);
  int sv[8];
#pragma unroll
  for (int j = 0; j < 8; ++j) sv[j] = (int)col2[((size_t)idx[j] << 6) + lane];
  int cnt[8];
#pragma unroll
  for (int j = 0; j < 8; ++j) {
    unsigned long long mb_ = __ballot(sv[j] != N);
    cnt[j] = __builtin_amdgcn_readfirstlane((int)__popcll(mb_));
  }
  unsigned hvA[2][8], hvB[2][8];
  AQ_ISSUE(0, hvA)
  AQ_ISSUE(1, hvB)
  AG_ACC(0, hvA)
  AQ_ISSUE(2, hvA)
  AG_ACC(1, hvB)
  AQ_ISSUE(3, hvB)
  AG_ACC(2, hvA)
  AQ_ISSUE(4, hvA)
  AG_ACC(3, hvB)
  AQ_ISSUE(5, hvB)
  AG_ACC(4, hvA)
  AQ_ISSUE(6, hvA)
  AG_ACC(5, hvB)
  AQ_ISSUE(7, hvB)
  AG_ACC(6, hvA)
  AG_ACC(7, hvB)

  int m = lane & 31;
#pragma unroll
  for (int p = 0; p < 4; ++p) {
    int nl = p * 2 + half;  // node-local 0..7, halves take alternate nodes
    int node = qb + nl;
    float acc = sb1[m];
    const float2* ar = (const float2*)(sA + ((wid << 3) + nl) * 64);  // broadcast
    const float2* wr = (const float2*)(sw1t + m * 66);                // 2-way (free)
#pragma unroll
    for (int k2 = 0; k2 < 32; ++k2) {
      float2 av = ar[k2];
      float2 wv = wr[k2];
      acc += av.x * wv.x + av.y * wv.y;
    }
    float t = ftanh(acc) * sw2[m];
#pragma unroll
    for (int o = 1; o < 32; o <<= 1) t += __shfl_xor(t, o);  // o=1..16: stays in half
    if (m == 0 && node < N) fout[node] = t + b2v;
  }
}

// ================= host =================

extern "C" void kernel_launch(void* const* d_in, const int* in_sizes, int n_in,
                              void* d_out, int out_size, void* d_ws, size_t ws_size,
                              hipStream_t stream) {
  const float* x   = (const float*)d_in[0];
  const int*   ei  = (const int*)d_in[1];
  const float* w1  = (const float*)d_in[2];
  const float* b1  = (const float*)d_in[3];
  const float* w2  = (const float*)d_in[4];
  const float* b2  = (const float*)d_in[5];
  const float* fw1 = (const float*)d_in[6];
  const float* fb1 = (const float*)d_in[7];
  const float* fw2 = (const float*)d_in[8];
  const float* fb2 = (const float*)d_in[9];
  float* out = (float*)d_out;

  int N = in_sizes[0] / 128;
  int E = in_sizes[1] / 2;
  const int* src = ei;
  const int* dst = ei + E;

  const int G   = 256;                // blocks for the edge scatter (write locality)
  const int NBK = (N + 127) / 128;    // 391 buckets

  char* p = (char*)d_ws;
  size_t off = 0;
  auto take = [&](size_t bytes) -> void* {
    void* r = p + off;
    off += (bytes + 255) & ~(size_t)255;
    return r;
  };
  int*            gcur = (int*)take((size_t)NBK * 4);
  float*          dinv = (float*)take((size_t)N * 4);
  unsigned*       e2   = (unsigned*)take((size_t)NBK * CAP * 4);
  unsigned short* col2 = (unsigned short*)take((size_t)N * DMAX * 2);
  unsigned short* h1   = (unsigned short*)take((size_t)(N + 1) * 64 * 2);  // +sentinel row N
  unsigned short* h2   = (unsigned short*)take((size_t)(N + 1) * 64 * 2);  // +sentinel row N
  (void)ws_size; (void)n_in; (void)out_size;

  // graph build: 3 kernels (fixed-capacity buckets -> line-granular writes)
  k_init<<<(NBK + TPB - 1) / TPB, TPB, 0, stream>>>(gcur, h1, h2, NBK, N);
  k_bscatter<<<G, TPB, 0, stream>>>(src, dst, gcur, e2, E, NBK);
  k_build<<<NBK, TPB, 0, stream>>>(e2, gcur, dinv, col2, N);

  // network: mm1 -> (agg1+mm2 fused) -> (agg2+FC fused)
  int gmm  = (N + 63) / 64;
  int gagg = (N + 31) / 32;  // 8 nodes/wave * 4 waves
  k_mm<128, true><<<gmm, TPB, 0, stream>>>(x, w1, dinv, h1, N);
  k_aggmm<<<gagg, TPB, 0, stream>>>(h1, col2, b1, w2, h2, N);
  k_aggfc<<<gagg, TPB, 0, stream>>>(h2, col2, b2, fw1, fb1, fw2, fb2, out, N);
}